// Round 16
// baseline (647.060 us; speedup 1.0000x reference)
//
#include <hip/hip_runtime.h>
#include <climits>

#define D 128

typedef float f32x4 __attribute__((ext_vector_type(4)));
typedef int   i32x2 __attribute__((ext_vector_type(2)));

// ---- CSR step 1: histogram + per-edge arrival rank (rank call-varying; sort canonicalizes) ----
__global__ __launch_bounds__(256) void hist_rank_kernel(const int* __restrict__ erow,
                                                        int* __restrict__ deg,
                                                        int* __restrict__ rank, int nE) {
    int e = blockIdx.x * 256 + threadIdx.x;
    if (e < nE) rank[e] = atomicAdd(&deg[erow[e]], 1);
}

// ---- scan phase 1: per-block scan of PADDED degrees (roundup8) ----
__global__ __launch_bounds__(256) void scan1_kernel(const int* __restrict__ deg,
                                                    int* __restrict__ rowptr,
                                                    int* __restrict__ blocksums, int n) {
    __shared__ int sd[256];
    const int t = threadIdx.x;
    const int idx = blockIdx.x * 1024 + t * 4;
    int4 v = make_int4(0, 0, 0, 0);
    if (idx + 3 < n) v = *(const int4*)&deg[idx];
    else {
        if (idx + 0 < n) v.x = deg[idx + 0];
        if (idx + 1 < n) v.y = deg[idx + 1];
        if (idx + 2 < n) v.z = deg[idx + 2];
        if (idx + 3 < n) v.w = deg[idx + 3];
    }
    v.x = (v.x + 7) & ~7; v.y = (v.y + 7) & ~7;   // pad rows to multiple of 8
    v.z = (v.z + 7) & ~7; v.w = (v.w + 7) & ~7;
    const int s = v.x + v.y + v.z + v.w;
    sd[t] = s;
    __syncthreads();
    for (int off = 1; off < 256; off <<= 1) {
        int tv = (t >= off) ? sd[t - off] : 0;
        __syncthreads();
        sd[t] += tv;
        __syncthreads();
    }
    const int excl = sd[t] - s;
    int a = excl + v.x, b = a + v.y, c = b + v.z, d = c + v.w;
    if (idx + 0 < n) rowptr[idx + 1] = a;
    if (idx + 1 < n) rowptr[idx + 2] = b;
    if (idx + 2 < n) rowptr[idx + 3] = c;
    if (idx + 3 < n) rowptr[idx + 4] = d;
    if (t == 255) blocksums[blockIdx.x] = sd[255];
}

// ---- scan phase 2: exclusive scan of block sums (nb <= 256) ----
__global__ __launch_bounds__(256) void scan2_kernel(int* __restrict__ blocksums, int nb) {
    __shared__ int sd[256];
    const int t = threadIdx.x;
    const int v = (t < nb) ? blocksums[t] : 0;
    sd[t] = v;
    __syncthreads();
    for (int off = 1; off < 256; off <<= 1) {
        int tv = (t >= off) ? sd[t - off] : 0;
        __syncthreads();
        sd[t] += tv;
        __syncthreads();
    }
    if (t < nb) blocksums[t] = sd[t] - v;   // exclusive
}

// ---- scan phase 3: add block offsets; finalize rowptr ----
__global__ __launch_bounds__(256) void scan3_kernel(int* __restrict__ rowptr,
                                                    const int* __restrict__ blocksums, int n) {
    int i = blockIdx.x * 256 + threadIdx.x;
    if (i < n) rowptr[i + 1] += blocksums[i >> 10];
    if (i == 0) rowptr[0] = 0;
}

// ---- CSR placement: one packed 8B record {col, valbits} per edge; no atomics ----
__global__ __launch_bounds__(256) void place_kernel(const int* __restrict__ erow,
                                                    const int* __restrict__ rank,
                                                    const int* __restrict__ ecol,
                                                    const float* __restrict__ ev,
                                                    const int* __restrict__ rowptr,
                                                    i32x2* __restrict__ cv, int nE) {
    int e = blockIdx.x * 256 + threadIdx.x;
    if (e >= nE) return;
    int pos = rowptr[erow[e]] + rank[e];
    i32x2 rec;
    rec.x = ecol[e];
    rec.y = __float_as_int(ev[e]);
    cv[pos] = rec;
}

// ---- canonicalize + pad-fill: wave rank-sort by u64(col,valbits); zero pads to row end ----
__global__ __launch_bounds__(256) void sortrow_wave_kernel(const int* __restrict__ rowptr,
                                                           const int* __restrict__ deg,
                                                           i32x2* __restrict__ cv, int n) {
    int row = blockIdx.x * 4 + (threadIdx.x >> 6);
    if (row >= n) return;
    const int lane = threadIdx.x & 63;
    const int s = rowptr[row], pe = rowptr[row + 1];
    const int dg = deg[row];
    const int npad = pe - s - dg;
    i32x2 zero; zero.x = 0; zero.y = 0;
    if (dg <= 64) {
        unsigned long long key = ~0ull;
        i32x2 rec = zero;
        if (lane < dg) {
            rec = cv[s + lane];
            key = ((unsigned long long)(unsigned)rec.x << 32) | (unsigned)rec.y;
        }
        int rank = 0;
        for (int i = 0; i < dg; ++i) {
            unsigned long long ki = __shfl(key, i);
            rank += (ki < key || (ki == key && i < lane)) ? 1 : 0;
        }
        if (lane < dg) cv[s + rank] = rec;    // wave-lockstep: reads precede writes
        if (lane < npad) cv[s + dg + lane] = zero;
    } else if (lane == 0) {                   // deg>64: ~never (deg ~ Poisson(16))
        for (int i = s + 1; i < s + dg; ++i) {
            i32x2 r_ = cv[i];
            unsigned long long k_ = ((unsigned long long)(unsigned)r_.x << 32) | (unsigned)r_.y;
            int j = i - 1;
            while (j >= s) {
                i32x2 rj = cv[j];
                unsigned long long kj = ((unsigned long long)(unsigned)rj.x << 32) | (unsigned)rj.y;
                if (kj <= k_) break;
                cv[j + 1] = rj;
                --j;
            }
            cv[j + 1] = r_;
        }
        for (int i = s + dg; i < pe; ++i) cv[i] = zero;
    }
}

// ---- persistent per-wave fused spmm+GEMM(+classify): grid-stride over 8-row groups ----
// 8192 waves total; each wave loops g, g+8192, ... Dual-stream gather per subwave (R14).
template <bool CLASSIFY>
__global__ __launch_bounds__(256) void spmm_gemm_kernel(
        const float* __restrict__ h, const int* __restrict__ rowptr,
        const i32x2* __restrict__ cv, const float* __restrict__ W,
        const float* __restrict__ Cls, float* __restrict__ O, int n, int nwaves) {
    const int wid0 = (blockIdx.x * 256 + threadIdx.x) >> 6;  // global wave id
    const int lane = threadIdx.x & 63;
    const int sw = lane >> 5;            // subwave 0/1
    const int l = lane & 31;
    const f32x4* hl = (const f32x4*)h + l;
    const int c0 = l * 4;
    const int sbase = sw << 5;
    const int ngroups = (n + 7) / 8;

    for (int g = wid0; g < ngroups; g += nwaves) {
        const int rbase = g * 8 + sw * 4;
        f32x4 rowdata[4];

        // ---- phase 1: gather 4 rows as 2 dual-stream pairs (rows padded: deg%8==0) ----
#pragma unroll
        for (int jp = 0; jp < 2; ++jp) {
            const int rA = rbase + jp * 2;
            const int rB = rA + 1;
            int kA = 0, eA = 0, kB = 0, eB = 0;
            if (rA < n) { kA = rowptr[rA]; eA = rowptr[rA + 1]; }
            if (rB < n) { kB = rowptr[rB]; eB = rowptr[rB + 1]; }
            f32x4 accA = (f32x4)(0.f), accB = (f32x4)(0.f);
            while (kA < eA || kB < eB) {
                i32x2 pA[8], pB[8];
                const bool doA = kA < eA, doB = kB < eB;
                if (doA) {
#pragma unroll
                    for (int u = 0; u < 8; ++u) pA[u] = cv[kA + u];
                }
                if (doB) {
#pragma unroll
                    for (int u = 0; u < 8; ++u) pB[u] = cv[kB + u];
                }
                if (doA) {
                    f32x4 hv[8];
#pragma unroll
                    for (int u = 0; u < 8; ++u) hv[u] = hl[(size_t)pA[u].x * 32];
#pragma unroll
                    for (int u = 0; u < 8; ++u) accA += __int_as_float(pA[u].y) * hv[u];
                    kA += 8;
                }
                if (doB) {
                    f32x4 hv[8];
#pragma unroll
                    for (int u = 0; u < 8; ++u) hv[u] = hl[(size_t)pB[u].x * 32];
#pragma unroll
                    for (int u = 0; u < 8; ++u) accB += __int_as_float(pB[u].y) * hv[u];
                    kB += 8;
                }
            }
            rowdata[jp * 2]     = accA;
            rowdata[jp * 2 + 1] = accB;
        }

        // ---- phase 2: GEMM epilogue via shfl-broadcast; lane owns out cols c0..c0+3 ----
        f32x4 oacc[4];
#pragma unroll
        for (int i = 0; i < 4; ++i) oacc[i] = (f32x4)(0.f);

        for (int k4 = 0; k4 < D / 4; ++k4) {
            const int srcl = sbase + k4;
#pragma unroll
            for (int kk = 0; kk < 4; ++kk) {
                const f32x4 w = *(const f32x4*)&W[(k4 * 4 + kk) * D + c0];
#pragma unroll
                for (int i = 0; i < 4; ++i) {
                    float hk = __shfl(rowdata[i][kk], srcl);
                    oacc[i] += hk * w;
                }
            }
        }

        if (!CLASSIFY) {
#pragma unroll
            for (int i = 0; i < 4; ++i) {
                const int r = rbase + i;
                if (r < n) {
                    f32x4 v;
                    v.x = fmaxf(oacc[i].x, 0.f); v.y = fmaxf(oacc[i].y, 0.f);
                    v.z = fmaxf(oacc[i].z, 0.f); v.w = fmaxf(oacc[i].w, 0.f);
                    *(f32x4*)&O[(size_t)r * D + c0] = v;
                }
            }
        } else {
            // relu in registers
#pragma unroll
            for (int i = 0; i < 4; ++i) {
                oacc[i].x = fmaxf(oacc[i].x, 0.f); oacc[i].y = fmaxf(oacc[i].y, 0.f);
                oacc[i].z = fmaxf(oacc[i].z, 0.f); oacc[i].w = fmaxf(oacc[i].w, 0.f);
            }
            // ---- phase 3: classify. lane l: class j = l&15, k-half kh = l>>4 ----
            const int j = l & 15;
            const int kh = l >> 4;
            float lg[4] = {0.f, 0.f, 0.f, 0.f};
            for (int m4 = 0; m4 < 16; ++m4) {
                const int srcl = sbase + kh * 16 + m4;
#pragma unroll
                for (int kk = 0; kk < 4; ++kk) {
                    const int k = kh * 64 + m4 * 4 + kk;
                    const float c = Cls[k * 16 + j];
#pragma unroll
                    for (int i = 0; i < 4; ++i) {
                        float hk = __shfl(oacc[i][kk], srcl);
                        lg[i] += hk * c;
                    }
                }
            }
#pragma unroll
            for (int i = 0; i < 4; ++i) lg[i] += __shfl_xor(lg[i], 16);
            if (kh == 0) {
#pragma unroll
                for (int i = 0; i < 4; ++i) {
                    const int r = rbase + i;
                    if (r < n) O[(size_t)r * 16 + j] = lg[i] > 0.f ? 1.f : 0.f;
                }
            }
        }
    }
}

extern "C" void kernel_launch(void* const* d_in, const int* in_sizes, int n_in,
                              void* d_out, int out_size, void* d_ws, size_t ws_size,
                              hipStream_t stream) {
    const float* x    = (const float*)d_in[0];
    const int*   erow = (const int*)d_in[1];
    const int*   ecol = (const int*)d_in[2];
    const float* ev   = (const float*)d_in[3];
    const float* w1   = (const float*)d_in[4];
    const float* w2   = (const float*)d_in[5];
    const float* cls  = (const float*)d_in[6];

    const int n  = in_sizes[0] / D;   // 100000
    const int nE = in_sizes[1];       // 1600000

    // workspace layout (cv sized nE + 8n for padding)
    char*  ws     = (char*)d_ws;
    float* h      = (float*)ws;                 ws += (size_t)n * D * 4;   // 51.2 MB
    int*   deg    = (int*)ws;                   ws += (size_t)n * 4;
    int*   rowptr = (int*)ws;                   ws += (size_t)(n + 1) * 4;
    int*   rank   = (int*)ws;                   ws += (size_t)nE * 4;
    i32x2* cv     = (i32x2*)ws;                 ws += ((size_t)nE + 8 * (size_t)n) * 8;
    int*   bsums  = (int*)ws;                   ws += 256 * 4;

    const int nb = (n + 1023) / 1024;   // 98 <= 256

    dim3 blk(256);
    dim3 egrid((nE + 255) / 256);
    dim3 ngrid((n + 255) / 256);
    dim3 wgrid((n + 3) / 4);          // sortrow: 1 wave per row

    // persistent fused kernel: exactly fill the device's wave slots
    const int SBLOCKS = 2048;          // 2048 blocks x 4 waves = 8192 waves
    const int NWAVES = SBLOCKS * 4;
    dim3 sgrid(SBLOCKS);

    // ---- CSR build (deterministic final order by (col,valbits); rows padded to 8) ----
    (void)hipMemsetAsync(deg, 0, (size_t)n * 4, stream);
    hist_rank_kernel<<<egrid, blk, 0, stream>>>(erow, deg, rank, nE);
    scan1_kernel<<<nb, blk, 0, stream>>>(deg, rowptr, bsums, n);
    scan2_kernel<<<1, blk, 0, stream>>>(bsums, nb);
    scan3_kernel<<<ngrid, blk, 0, stream>>>(rowptr, bsums, n);
    place_kernel<<<egrid, blk, 0, stream>>>(erow, rank, ecol, ev, rowptr, cv, nE);
    sortrow_wave_kernel<<<wgrid, blk, 0, stream>>>(rowptr, deg, cv, n);

    // ---- layer 1: h = relu(spmm(x) @ w1) ----
    spmm_gemm_kernel<false><<<sgrid, blk, 0, stream>>>(x, rowptr, cv, w1, nullptr, h, n,
                                                       NWAVES);

    // ---- layer 2 + classifier: out = (relu(spmm(h) @ w2) @ cls > 0) ----
    spmm_gemm_kernel<true><<<sgrid, blk, 0, stream>>>(h, rowptr, cv, w2, cls,
                                                      (float*)d_out, n, NWAVES);
}

// Round 17
// 424.650 us; speedup vs baseline: 1.5237x; 1.5237x over previous
//
#include <hip/hip_runtime.h>
#include <climits>

#define D 128

typedef float f32x4 __attribute__((ext_vector_type(4)));
typedef int   i32x2 __attribute__((ext_vector_type(2)));

// ---- CSR step 1: histogram + per-edge arrival rank (rank call-varying; sort canonicalizes) ----
__global__ __launch_bounds__(256) void hist_rank_kernel(const int* __restrict__ erow,
                                                        int* __restrict__ deg,
                                                        int* __restrict__ rank, int nE) {
    int e = blockIdx.x * 256 + threadIdx.x;
    if (e < nE) rank[e] = atomicAdd(&deg[erow[e]], 1);
}

// ---- scan phase 1: per-block scan of PADDED degrees (roundup8) ----
__global__ __launch_bounds__(256) void scan1_kernel(const int* __restrict__ deg,
                                                    int* __restrict__ rowptr,
                                                    int* __restrict__ blocksums, int n) {
    __shared__ int sd[256];
    const int t = threadIdx.x;
    const int idx = blockIdx.x * 1024 + t * 4;
    int4 v = make_int4(0, 0, 0, 0);
    if (idx + 3 < n) v = *(const int4*)&deg[idx];
    else {
        if (idx + 0 < n) v.x = deg[idx + 0];
        if (idx + 1 < n) v.y = deg[idx + 1];
        if (idx + 2 < n) v.z = deg[idx + 2];
        if (idx + 3 < n) v.w = deg[idx + 3];
    }
    v.x = (v.x + 7) & ~7; v.y = (v.y + 7) & ~7;   // pad rows to multiple of 8
    v.z = (v.z + 7) & ~7; v.w = (v.w + 7) & ~7;
    const int s = v.x + v.y + v.z + v.w;
    sd[t] = s;
    __syncthreads();
    for (int off = 1; off < 256; off <<= 1) {
        int tv = (t >= off) ? sd[t - off] : 0;
        __syncthreads();
        sd[t] += tv;
        __syncthreads();
    }
    const int excl = sd[t] - s;
    int a = excl + v.x, b = a + v.y, c = b + v.z, d = c + v.w;
    if (idx + 0 < n) rowptr[idx + 1] = a;
    if (idx + 1 < n) rowptr[idx + 2] = b;
    if (idx + 2 < n) rowptr[idx + 3] = c;
    if (idx + 3 < n) rowptr[idx + 4] = d;
    if (t == 255) blocksums[blockIdx.x] = sd[255];
}

// ---- scan phase 2+3 merged: every block redundantly scans the <=256 block sums in LDS ----
__global__ __launch_bounds__(256) void scan3_kernel(int* __restrict__ rowptr,
                                                    const int* __restrict__ blocksums,
                                                    int n, int nb) {
    __shared__ int sd[256];
    const int t = threadIdx.x;
    const int v = (t < nb) ? blocksums[t] : 0;
    sd[t] = v;
    __syncthreads();
    for (int off = 1; off < 256; off <<= 1) {
        int tv = (t >= off) ? sd[t - off] : 0;
        __syncthreads();
        sd[t] += tv;
        __syncthreads();
    }
    const int excl = sd[t] - v;     // exclusive sum for block t
    __syncthreads();
    sd[t] = excl;
    __syncthreads();
    int i = blockIdx.x * 256 + t;
    if (i < n) rowptr[i + 1] += sd[i >> 10];
    if (i == 0) rowptr[0] = 0;
}

// ---- CSR placement: one packed 8B record {col, valbits} per edge; no atomics ----
__global__ __launch_bounds__(256) void place_kernel(const int* __restrict__ erow,
                                                    const int* __restrict__ rank,
                                                    const int* __restrict__ ecol,
                                                    const float* __restrict__ ev,
                                                    const int* __restrict__ rowptr,
                                                    i32x2* __restrict__ cv, int nE) {
    int e = blockIdx.x * 256 + threadIdx.x;
    if (e >= nE) return;
    int pos = rowptr[erow[e]] + rank[e];
    i32x2 rec;
    rec.x = ecol[e];
    rec.y = __float_as_int(ev[e]);
    cv[pos] = rec;
}

// ---- canonicalize + pad-fill: 2 rows per wave (32-lane rank-sort per half) ----
__global__ __launch_bounds__(256) void sortrow_wave_kernel(const int* __restrict__ rowptr,
                                                           const int* __restrict__ deg,
                                                           i32x2* __restrict__ cv, int n) {
    const int wid = (blockIdx.x * 256 + threadIdx.x) >> 6;
    const int lane = threadIdx.x & 63;
    const int rA = wid * 2, rB = rA + 1;
    if (rA >= n) return;
    const int dgA = deg[rA];
    const int dgB = (rB < n) ? deg[rB] : 0;
    i32x2 zero; zero.x = 0; zero.y = 0;

    if (dgA <= 32 && dgB <= 32) {
        const int half = lane >> 5;
        const int l = lane & 31;
        const int row = rA + half;
        const int dg = half ? dgB : dgA;
        if (row < n) {
            const int s = rowptr[row], pe = rowptr[row + 1];
            const int npad = pe - s - dg;
            unsigned long long key = ~0ull;
            i32x2 rec = zero;
            if (l < dg) {
                rec = cv[s + l];
                key = ((unsigned long long)(unsigned)rec.x << 32) | (unsigned)rec.y;
            }
            int rank = 0;
            for (int i = 0; i < dg; ++i) {
                unsigned long long ki = __shfl(key, i, 32);
                rank += (ki < key || (ki == key && i < l)) ? 1 : 0;
            }
            if (l < dg) cv[s + rank] = rec;    // half-wave lockstep: reads precede writes
            if (l < npad) cv[s + dg + l] = zero;
        }
    } else {
        // rare: some row >32 — handle both rows sequentially with the full wave
        for (int rr = 0; rr < 2; ++rr) {
            const int row = rA + rr;
            if (row >= n) continue;
            const int dg = deg[row];
            const int s = rowptr[row], pe = rowptr[row + 1];
            const int npad = pe - s - dg;
            if (dg <= 64) {
                unsigned long long key = ~0ull;
                i32x2 rec = zero;
                if (lane < dg) {
                    rec = cv[s + lane];
                    key = ((unsigned long long)(unsigned)rec.x << 32) | (unsigned)rec.y;
                }
                int rank = 0;
                for (int i = 0; i < dg; ++i) {
                    unsigned long long ki = __shfl(key, i);
                    rank += (ki < key || (ki == key && i < lane)) ? 1 : 0;
                }
                if (lane < dg) cv[s + rank] = rec;
                if (lane < npad) cv[s + dg + lane] = zero;
            } else if (lane == 0) {
                for (int i = s + 1; i < s + dg; ++i) {
                    i32x2 r_ = cv[i];
                    unsigned long long k_ =
                        ((unsigned long long)(unsigned)r_.x << 32) | (unsigned)r_.y;
                    int j = i - 1;
                    while (j >= s) {
                        i32x2 rj = cv[j];
                        unsigned long long kj =
                            ((unsigned long long)(unsigned)rj.x << 32) | (unsigned)rj.y;
                        if (kj <= k_) break;
                        cv[j + 1] = rj;
                        --j;
                    }
                    cv[j + 1] = r_;
                }
                for (int i = s + dg; i < pe; ++i) cv[i] = zero;
            }
        }
    }
}

// ---- per-wave fused spmm+GEMM(+classify): 8 rows/wave, DUAL-STREAM gather, no LDS (R14) ----
template <bool CLASSIFY>
__global__ __launch_bounds__(256) void spmm_gemm_kernel(
        const float* __restrict__ h, const int* __restrict__ rowptr,
        const i32x2* __restrict__ cv, const float* __restrict__ W,
        const float* __restrict__ Cls, float* __restrict__ O, int n) {
    const int wid = (blockIdx.x * 256 + threadIdx.x) >> 6;   // global wave id
    const int lane = threadIdx.x & 63;
    const int sw = lane >> 5;            // subwave 0/1
    const int l = lane & 31;
    const int row0 = wid * 8;
    if (row0 >= n) return;
    const int rbase = row0 + sw * 4;

    const f32x4* hl = (const f32x4*)h + l;
    f32x4 rowdata[4];

    // ---- phase 1: gather 4 rows as 2 dual-stream pairs (rows padded: deg%8==0) ----
#pragma unroll
    for (int jp = 0; jp < 2; ++jp) {
        const int rA = rbase + jp * 2;
        const int rB = rA + 1;
        int kA = 0, eA = 0, kB = 0, eB = 0;
        if (rA < n) { kA = rowptr[rA]; eA = rowptr[rA + 1]; }
        if (rB < n) { kB = rowptr[rB]; eB = rowptr[rB + 1]; }
        f32x4 accA = (f32x4)(0.f), accB = (f32x4)(0.f);
        while (kA < eA || kB < eB) {
            i32x2 pA[8], pB[8];
            const bool doA = kA < eA, doB = kB < eB;
            if (doA) {
#pragma unroll
                for (int u = 0; u < 8; ++u) pA[u] = cv[kA + u];
            }
            if (doB) {
#pragma unroll
                for (int u = 0; u < 8; ++u) pB[u] = cv[kB + u];
            }
            if (doA) {
                f32x4 hv[8];
#pragma unroll
                for (int u = 0; u < 8; ++u) hv[u] = hl[(size_t)pA[u].x * 32];
#pragma unroll
                for (int u = 0; u < 8; ++u) accA += __int_as_float(pA[u].y) * hv[u];
                kA += 8;
            }
            if (doB) {
                f32x4 hv[8];
#pragma unroll
                for (int u = 0; u < 8; ++u) hv[u] = hl[(size_t)pB[u].x * 32];
#pragma unroll
                for (int u = 0; u < 8; ++u) accB += __int_as_float(pB[u].y) * hv[u];
                kB += 8;
            }
        }
        rowdata[jp * 2]     = accA;
        rowdata[jp * 2 + 1] = accB;
    }

    // ---- phase 2: GEMM epilogue via shfl-broadcast; lane owns out cols c0..c0+3 ----
    const int c0 = l * 4;
    const int sbase = sw << 5;
    f32x4 oacc[4];
#pragma unroll
    for (int i = 0; i < 4; ++i) oacc[i] = (f32x4)(0.f);

    for (int k4 = 0; k4 < D / 4; ++k4) {
        const int srcl = sbase + k4;
#pragma unroll
        for (int kk = 0; kk < 4; ++kk) {
            const f32x4 w = *(const f32x4*)&W[(k4 * 4 + kk) * D + c0];
#pragma unroll
            for (int i = 0; i < 4; ++i) {
                float hk = __shfl(rowdata[i][kk], srcl);
                oacc[i] += hk * w;
            }
        }
    }

    if (!CLASSIFY) {
#pragma unroll
        for (int i = 0; i < 4; ++i) {
            const int r = rbase + i;
            if (r < n) {
                f32x4 v;
                v.x = fmaxf(oacc[i].x, 0.f); v.y = fmaxf(oacc[i].y, 0.f);
                v.z = fmaxf(oacc[i].z, 0.f); v.w = fmaxf(oacc[i].w, 0.f);
                *(f32x4*)&O[(size_t)r * D + c0] = v;
            }
        }
    } else {
        // relu in registers
#pragma unroll
        for (int i = 0; i < 4; ++i) {
            oacc[i].x = fmaxf(oacc[i].x, 0.f); oacc[i].y = fmaxf(oacc[i].y, 0.f);
            oacc[i].z = fmaxf(oacc[i].z, 0.f); oacc[i].w = fmaxf(oacc[i].w, 0.f);
        }
        // ---- phase 3: classify. lane l: class j = l&15, k-half kh = l>>4 ----
        const int j = l & 15;
        const int kh = l >> 4;
        float lg[4] = {0.f, 0.f, 0.f, 0.f};
        for (int m4 = 0; m4 < 16; ++m4) {
            const int srcl = sbase + kh * 16 + m4;
#pragma unroll
            for (int kk = 0; kk < 4; ++kk) {
                const int k = kh * 64 + m4 * 4 + kk;
                const float c = Cls[k * 16 + j];
#pragma unroll
                for (int i = 0; i < 4; ++i) {
                    float hk = __shfl(oacc[i][kk], srcl);
                    lg[i] += hk * c;
                }
            }
        }
#pragma unroll
        for (int i = 0; i < 4; ++i) lg[i] += __shfl_xor(lg[i], 16);
        if (kh == 0) {
#pragma unroll
            for (int i = 0; i < 4; ++i) {
                const int r = rbase + i;
                if (r < n) O[(size_t)r * 16 + j] = lg[i] > 0.f ? 1.f : 0.f;
            }
        }
    }
}

extern "C" void kernel_launch(void* const* d_in, const int* in_sizes, int n_in,
                              void* d_out, int out_size, void* d_ws, size_t ws_size,
                              hipStream_t stream) {
    const float* x    = (const float*)d_in[0];
    const int*   erow = (const int*)d_in[1];
    const int*   ecol = (const int*)d_in[2];
    const float* ev   = (const float*)d_in[3];
    const float* w1   = (const float*)d_in[4];
    const float* w2   = (const float*)d_in[5];
    const float* cls  = (const float*)d_in[6];

    const int n  = in_sizes[0] / D;   // 100000
    const int nE = in_sizes[1];       // 1600000

    // workspace layout (cv sized nE + 8n for padding)
    char*  ws     = (char*)d_ws;
    float* h      = (float*)ws;                 ws += (size_t)n * D * 4;   // 51.2 MB
    int*   deg    = (int*)ws;                   ws += (size_t)n * 4;
    int*   rowptr = (int*)ws;                   ws += (size_t)(n + 1) * 4;
    int*   rank   = (int*)ws;                   ws += (size_t)nE * 4;
    i32x2* cv     = (i32x2*)ws;                 ws += ((size_t)nE + 8 * (size_t)n) * 8;
    int*   bsums  = (int*)ws;                   ws += 256 * 4;

    const int nb = (n + 1023) / 1024;   // 98 <= 256

    dim3 blk(256);
    dim3 egrid((nE + 255) / 256);
    dim3 ngrid((n + 255) / 256);
    dim3 wgrid((n / 2 + 3) / 4);      // sortrow: 2 rows per wave, 4 waves/block
    dim3 sgrid((n + 31) / 32);        // spmm_gemm: 32 rows per block (8 per wave)

    // ---- CSR build (deterministic final order by (col,valbits); rows padded to 8) ----
    (void)hipMemsetAsync(deg, 0, (size_t)n * 4, stream);
    hist_rank_kernel<<<egrid, blk, 0, stream>>>(erow, deg, rank, nE);
    scan1_kernel<<<nb, blk, 0, stream>>>(deg, rowptr, bsums, n);
    scan3_kernel<<<ngrid, blk, 0, stream>>>(rowptr, bsums, n, nb);
    place_kernel<<<egrid, blk, 0, stream>>>(erow, rank, ecol, ev, rowptr, cv, nE);
    sortrow_wave_kernel<<<wgrid, blk, 0, stream>>>(rowptr, deg, cv, n);

    // ---- layer 1: h = relu(spmm(x) @ w1) ----
    spmm_gemm_kernel<false><<<sgrid, blk, 0, stream>>>(x, rowptr, cv, w1, nullptr, h, n);

    // ---- layer 2 + classifier: out = (relu(spmm(h) @ w2) @ cls > 0) ----
    spmm_gemm_kernel<true><<<sgrid, blk, 0, stream>>>(h, rowptr, cv, w2, cls,
                                                      (float*)d_out, n);
}